// Round 1
// baseline (362.197 us; speedup 1.0000x reference)
//
#include <hip/hip_runtime.h>

// MQA: B=2, S=2048, HID=2048, H=16, D=128 (single KV head), causal.
// Pipeline: cast -> fused QKV NT-GEMM (bf16 MFMA) -> V transpose ->
//           flash attention (LDS-staged KV, online softmax) -> out NT-GEMM.

#define S_LEN 2048
#define HID_  2048
#define D_    128
#define NQKV  2304   // 2048 Q + 128 K + 128 V columns

typedef __attribute__((ext_vector_type(8))) short bf16x8;
typedef __attribute__((ext_vector_type(4))) float f32x4;

__device__ __forceinline__ unsigned short f2b(float f) {
  union { float f; unsigned int u; } a; a.f = f;
  unsigned int u = a.u;
  return (unsigned short)((u + 0x7fffu + ((u >> 16) & 1u)) >> 16);  // RNE
}

__device__ __forceinline__ void load_lds16(const void* g, void* l) {
  __builtin_amdgcn_global_load_lds(
      (const __attribute__((address_space(1))) void*)g,
      (__attribute__((address_space(3))) void*)l, 16, 0, 0);
}

__device__ __forceinline__ f32x4 mfma16(bf16x8 a, bf16x8 b, f32x4 c) {
  return __builtin_amdgcn_mfma_f32_16x16x32_bf16(a, b, c, 0, 0, 0);
}

// ---------------- casts / packing ----------------

__global__ void cast_f32_bf16_k(const float* __restrict__ in,
                                unsigned short* __restrict__ out, int n4) {
  const int idx = blockIdx.x * 256 + threadIdx.x;
  if (idx < n4) {
    const float4 v = ((const float4*)in)[idx];
    ushort4 o;
    o.x = f2b(v.x); o.y = f2b(v.y); o.z = f2b(v.z); o.w = f2b(v.w);
    ((ushort4*)out)[idx] = o;
  }
}

// Wcat rows: [0,2048)=Wq, [2048,2176)=Wk, [2176,2304)=Wv ; bcat likewise.
__global__ void build_wcat_k(const float* __restrict__ Wq,
                             const float* __restrict__ Wk,
                             const float* __restrict__ Wv,
                             const float* __restrict__ bq,
                             const float* __restrict__ bk,
                             const float* __restrict__ bv,
                             unsigned short* __restrict__ Wcat,
                             float* __restrict__ bcat) {
  const int idx = blockIdx.x * 256 + threadIdx.x;   // 4608*256 = 1,179,648
  const int i = idx * 4;                            // elem index, 2304*2048 total
  const int row = i >> 11;
  const int col = i & 2047;
  const float* src;
  if (row < 2048)      src = Wq + (size_t)row * 2048 + col;
  else if (row < 2176) src = Wk + (size_t)(row - 2048) * 2048 + col;
  else                 src = Wv + (size_t)(row - 2176) * 2048 + col;
  const float4 v = *(const float4*)src;
  ushort4 o;
  o.x = f2b(v.x); o.y = f2b(v.y); o.z = f2b(v.z); o.w = f2b(v.w);
  *(ushort4*)(Wcat + i) = o;
  if (idx < NQKV)
    bcat[idx] = (idx < 2048) ? bq[idx] : (idx < 2176) ? bk[idx - 2048] : bv[idx - 2176];
}

// Vt[b][d][s] = QKV[b*S+s][2176+d]  (coalesced writes, L2-served reads)
__global__ void transpose_v(const unsigned short* __restrict__ QKV,
                            unsigned short* __restrict__ Vt) {
  const int idx = blockIdx.x * 256 + threadIdx.x;   // 2*128*2048 = 524288
  const int s = idx & (S_LEN - 1);
  const int d = (idx >> 11) & (D_ - 1);
  const int b = idx >> 18;
  Vt[idx] = QKV[(size_t)(b * S_LEN + s) * NQKV + 2176 + d];
}

// ---------------- NT GEMM: C[m,n] = sum_k A[m,k]*B[n,k] + bias[n] ----------------
// m97 structure: 128x128 tile, BK=32, 4 waves (2x2), global_load_lds width 16.

template <int OUT_F32>
__global__ __launch_bounds__(256)
void gemm_nt(const unsigned short* __restrict__ A,
             const unsigned short* __restrict__ Bm,
             const float* __restrict__ bias,
             void* __restrict__ Cv,
             int M, int N, int K) {
  __shared__ unsigned short As[128 * 32];
  __shared__ unsigned short Bs[128 * 32];
  const int tid  = threadIdx.x;
  const int lane = tid & 63;
  const int wv   = tid >> 6;
  const int wr   = wv >> 1, wc = wv & 1;
  const int g    = lane >> 4, r = lane & 15;
  const int m0   = blockIdx.y * 128;
  const int n0   = blockIdx.x * 128;

  const unsigned short* ga0 = A  + (size_t)(m0 + (tid >> 2)) * K + (tid & 3) * 8;
  const unsigned short* ga1 = ga0 + (size_t)64 * K;
  const unsigned short* gb0 = Bm + (size_t)(n0 + (tid >> 2)) * K + (tid & 3) * 8;
  const unsigned short* gb1 = gb0 + (size_t)64 * K;

  f32x4 acc[4][4] = {};

  for (int k0 = 0; k0 < K; k0 += 32) {
    __syncthreads();
    load_lds16(ga0 + k0, &As[tid * 8]);
    load_lds16(ga1 + k0, &As[2048 + tid * 8]);
    load_lds16(gb0 + k0, &Bs[tid * 8]);
    load_lds16(gb1 + k0, &Bs[2048 + tid * 8]);
    __syncthreads();
    bf16x8 af[4], bfr[4];
#pragma unroll
    for (int i = 0; i < 4; ++i)
      af[i] = *(const bf16x8*)&As[(wr * 64 + i * 16 + r) * 32 + g * 8];
#pragma unroll
    for (int i = 0; i < 4; ++i)
      bfr[i] = *(const bf16x8*)&Bs[(wc * 64 + i * 16 + r) * 32 + g * 8];
#pragma unroll
    for (int i = 0; i < 4; ++i)
#pragma unroll
      for (int j = 0; j < 4; ++j)
        acc[i][j] = mfma16(af[i], bfr[j], acc[i][j]);
  }

#pragma unroll
  for (int i = 0; i < 4; ++i) {
    const int row = m0 + wr * 64 + i * 16 + g * 4;
#pragma unroll
    for (int j = 0; j < 4; ++j) {
      const int col = n0 + wc * 64 + j * 16 + r;
      const float bb = bias[col];
#pragma unroll
      for (int e = 0; e < 4; ++e) {
        const float v = acc[i][j][e] + bb;
        if (OUT_F32) ((float*)Cv)[(size_t)(row + e) * N + col] = v;
        else ((unsigned short*)Cv)[(size_t)(row + e) * N + col] = f2b(v);
      }
    }
  }
}

// ---------------- flash attention (causal, MQA) ----------------
// Block: 64 Q rows of one (b,h); 4 waves x 16 rows. KV tiles of 32 staged in LDS.
// K tile XOR-swizzled (source-side, rule 21) to kill D=128 row-stride conflicts.

__global__ __launch_bounds__(256)
void mqa_attn(const unsigned short* __restrict__ QKV,
              const unsigned short* __restrict__ Vt,
              unsigned short* __restrict__ Ob) {
  __shared__ unsigned short Ks[32 * 128];     // [kv][d], 16B-chunk XOR swizzle
  __shared__ unsigned short Vs[128 * 32];     // [d][kv] linear
  __shared__ unsigned short Pl[4][16 * 40];   // per-wave P tile [q][kv], stride 40

  const int tid  = threadIdx.x;
  const int lane = tid & 63;
  const int wv   = tid >> 6;
  const int g    = lane >> 4;
  const int c    = lane & 15;
  const int qt   = blockIdx.x;       // 0..31
  const int bh   = blockIdx.y;       // 0..31
  const int b    = bh >> 4;
  const int h    = bh & 15;
  const int qrow0 = qt * 64 + wv * 16;

  unsigned short* pw = &Pl[wv][0];

  // Q fragments (A-layout: row = lane&15, k-group = lane>>4), held all loop
  bf16x8 qf[4];
  {
    const unsigned short* qp =
        QKV + (size_t)(b * S_LEN + qrow0 + c) * NQKV + h * D_ + g * 8;
#pragma unroll
    for (int kk = 0; kk < 4; ++kk) qf[kk] = *(const bf16x8*)(qp + kk * 32);
  }

  const unsigned short* kbase = QKV + (size_t)(b * S_LEN) * NQKV + 2048;
  const unsigned short* vtb   = Vt + (size_t)b * D_ * S_LEN;

  f32x4 acc[8];
#pragma unroll
  for (int i = 0; i < 8; ++i) { acc[i][0]=0.f; acc[i][1]=0.f; acc[i][2]=0.f; acc[i][3]=0.f; }
  float mrow[4] = {-__builtin_inff(), -__builtin_inff(), -__builtin_inff(), -__builtin_inff()};
  float lrow[4] = {0.f, 0.f, 0.f, 0.f};

  const float sscale = 0.08838834764831845f * 1.4426950408889634f;  // scale*log2(e)
  const int ntiles = (qt + 1) * 2;

  // staging addresses (chunk = tid and tid+256)
  const int kr0 = tid >> 4;              // K tile row 0..15
  const int kr1 = kr0 + 16;
  const int kcb = (tid & 15) * 16;       // byte col in 256B row
  const char* ksrc0 = (const char*)(kbase + (size_t)kr0 * NQKV) + (kcb ^ ((kr0 & 7) << 4));
  const char* ksrc1 = (const char*)(kbase + (size_t)kr1 * NQKV) + (kcb ^ ((kr1 & 7) << 4));
  const int vr0 = tid >> 2;              // Vt tile row (=d) 0..63
  const int vr1 = vr0 + 64;
  const int vcb = (tid & 3) * 16;
  const char* vsrc0 = (const char*)(vtb + (size_t)vr0 * S_LEN) + vcb;
  const char* vsrc1 = (const char*)(vtb + (size_t)vr1 * S_LEN) + vcb;

  for (int t = 0; t < ntiles; ++t) {
    const int kv0 = t * 32;
    __syncthreads();
    load_lds16(ksrc0 + (size_t)kv0 * NQKV * 2, (char*)Ks + tid * 16);
    load_lds16(ksrc1 + (size_t)kv0 * NQKV * 2, (char*)Ks + 4096 + tid * 16);
    load_lds16(vsrc0 + kv0 * 2, (char*)Vs + tid * 16);
    load_lds16(vsrc1 + kv0 * 2, (char*)Vs + 4096 + tid * 16);
    __syncthreads();

    // QK^T : s0 = cols kv0..kv0+15, s1 = kv0+16..kv0+31
    f32x4 s0 = {0.f,0.f,0.f,0.f}, s1 = {0.f,0.f,0.f,0.f};
    const int xr = (c & 7) << 4;   // same for rows c and c+16
#pragma unroll
    for (int kk = 0; kk < 4; ++kk) {
      const int cb = kk * 64 + g * 16;
      bf16x8 k0 = *(const bf16x8*)((const char*)Ks + c * 256 + (cb ^ xr));
      bf16x8 k1 = *(const bf16x8*)((const char*)Ks + (c + 16) * 256 + (cb ^ xr));
      s0 = mfma16(qf[kk], k0, s0);
      s1 = mfma16(qf[kk], k1, s1);
    }

    // online softmax (exp2 domain); D-layout: row=4g+j, col=c(+16)
#pragma unroll
    for (int j = 0; j < 4; ++j) {
      const int qg = qrow0 + 4 * g + j;
      float a0 = (kv0 + c      <= qg) ? s0[j] * sscale : -__builtin_inff();
      float a1 = (kv0 + 16 + c <= qg) ? s1[j] * sscale : -__builtin_inff();
      float pm = fmaxf(a0, a1);
      pm = fmaxf(pm, __shfl_xor(pm, 1));
      pm = fmaxf(pm, __shfl_xor(pm, 2));
      pm = fmaxf(pm, __shfl_xor(pm, 4));
      pm = fmaxf(pm, __shfl_xor(pm, 8));
      const float mnew = fmaxf(mrow[j], pm);
      const float scal = __builtin_amdgcn_exp2f(mrow[j] - mnew);
      mrow[j] = mnew;
      const float p0 = __builtin_amdgcn_exp2f(a0 - mnew);
      const float p1 = __builtin_amdgcn_exp2f(a1 - mnew);
      float rs = p0 + p1;
      rs += __shfl_xor(rs, 1);
      rs += __shfl_xor(rs, 2);
      rs += __shfl_xor(rs, 4);
      rs += __shfl_xor(rs, 8);
      lrow[j] = lrow[j] * scal + rs;
#pragma unroll
      for (int nf = 0; nf < 8; ++nf) acc[nf][j] *= scal;
      pw[(4 * g + j) * 40 + c]      = f2b(p0);
      pw[(4 * g + j) * 40 + c + 16] = f2b(p1);
    }
    asm volatile("s_waitcnt lgkmcnt(0)" ::: "memory");   // P writes visible in-wave
    bf16x8 pf = *(const bf16x8*)&pw[c * 40 + g * 8];     // A-layout P[q=c][kv=8g+e]

    // PV: acc[nf] += P(16x32) * V(32x16)
#pragma unroll
    for (int nf = 0; nf < 8; ++nf) {
      bf16x8 vf = *(const bf16x8*)((const char*)Vs + (size_t)(nf * 16 + c) * 64 + g * 16);
      acc[nf] = mfma16(pf, vf, acc[nf]);
    }
  }

  // epilogue: normalize and store bf16 [4096][2048]
  unsigned short* op = Ob + (size_t)(b * S_LEN + qrow0 + 4 * g) * HID_ + h * D_ + c;
#pragma unroll
  for (int j = 0; j < 4; ++j) {
    const float inv = 1.0f / lrow[j];
#pragma unroll
    for (int nf = 0; nf < 8; ++nf)
      op[(size_t)j * HID_ + nf * 16] = f2b(acc[nf][j] * inv);
  }
}

// ---------------- launcher ----------------

extern "C" void kernel_launch(void* const* d_in, const int* in_sizes, int n_in,
                              void* d_out, int out_size, void* d_ws, size_t ws_size,
                              hipStream_t stream) {
  (void)in_sizes; (void)n_in; (void)out_size; (void)ws_size;
  const float* x  = (const float*)d_in[0];
  // d_in[1] = mask (causal, hardcoded)
  const float* Wq = (const float*)d_in[2];
  const float* bq = (const float*)d_in[3];
  const float* Wk = (const float*)d_in[4];
  const float* bk = (const float*)d_in[5];
  const float* Wv = (const float*)d_in[6];
  const float* bv = (const float*)d_in[7];
  const float* Wo = (const float*)d_in[8];
  const float* bo = (const float*)d_in[9];
  float* out = (float*)d_out;

  char* p = (char*)d_ws;
  unsigned short* xb   = (unsigned short*)p;  p += (size_t)4096 * 2048 * 2;  // 16.8 MB
  unsigned short* Wcat = (unsigned short*)p;  p += (size_t)2304 * 2048 * 2;  //  9.4 MB
  float*          bcat = (float*)p;           p += 16384;
  unsigned short* Wob  = (unsigned short*)p;  p += (size_t)2048 * 2048 * 2;  //  8.4 MB
  unsigned short* QKV  = (unsigned short*)p;  p += (size_t)4096 * 2304 * 2;  // 18.9 MB
  unsigned short* Vt   = (unsigned short*)p;  p += (size_t)2 * 128 * 2048 * 2; // 1 MB
  unsigned short* Ob   = xb;  // xb dead after gemm1; reuse for attention output

  cast_f32_bf16_k<<<8192, 256, 0, stream>>>(x, xb, 2097152);
  build_wcat_k<<<4608, 256, 0, stream>>>(Wq, Wk, Wv, bq, bk, bv, Wcat, bcat);
  cast_f32_bf16_k<<<4096, 256, 0, stream>>>(Wo, Wob, 1048576);
  gemm_nt<0><<<dim3(18, 32), 256, 0, stream>>>(xb, Wcat, bcat, QKV, 4096, NQKV, 2048);
  transpose_v<<<2048, 256, 0, stream>>>(QKV, Vt);
  mqa_attn<<<dim3(32, 32), 256, 0, stream>>>(QKV, Vt, Ob);
  gemm_nt<1><<<dim3(16, 32), 256, 0, stream>>>(Ob, Wob, bo, out, 4096, 2048, 2048);
}

// Round 2
// 317.513 us; speedup vs baseline: 1.1407x; 1.1407x over previous
//
#include <hip/hip_runtime.h>

// MQA: B=2, S=2048, HID=2048, H=16, D=128 (single KV head), causal.
// Pipeline: cast -> fused QKV NT-GEMM (bf16 MFMA) -> V transpose ->
//           flash attention (dbuf LDS KV, swizzled, online softmax) -> out GEMM.

#define S_LEN 2048
#define HID_  2048
#define D_    128
#define NQKV  2304   // 2048 Q + 128 K + 128 V columns

typedef __attribute__((ext_vector_type(8))) short bf16x8;
typedef __attribute__((ext_vector_type(4))) float f32x4;

__device__ __forceinline__ unsigned short f2b(float f) {
  union { float f; unsigned int u; } a; a.f = f;
  unsigned int u = a.u;
  return (unsigned short)((u + 0x7fffu + ((u >> 16) & 1u)) >> 16);  // RNE
}

__device__ __forceinline__ void load_lds16(const void* g, void* l) {
  __builtin_amdgcn_global_load_lds(
      (const __attribute__((address_space(1))) void*)g,
      (__attribute__((address_space(3))) void*)l, 16, 0, 0);
}

__device__ __forceinline__ f32x4 mfma16(bf16x8 a, bf16x8 b, f32x4 c) {
  return __builtin_amdgcn_mfma_f32_16x16x32_bf16(a, b, c, 0, 0, 0);
}

// ---------------- casts / packing ----------------

__global__ void cast_f32_bf16_k(const float* __restrict__ in,
                                unsigned short* __restrict__ out, int n4) {
  const int idx = blockIdx.x * 256 + threadIdx.x;
  if (idx < n4) {
    const float4 v = ((const float4*)in)[idx];
    ushort4 o;
    o.x = f2b(v.x); o.y = f2b(v.y); o.z = f2b(v.z); o.w = f2b(v.w);
    ((ushort4*)out)[idx] = o;
  }
}

__global__ void build_wcat_k(const float* __restrict__ Wq,
                             const float* __restrict__ Wk,
                             const float* __restrict__ Wv,
                             const float* __restrict__ bq,
                             const float* __restrict__ bk,
                             const float* __restrict__ bv,
                             unsigned short* __restrict__ Wcat,
                             float* __restrict__ bcat) {
  const int idx = blockIdx.x * 256 + threadIdx.x;
  const int i = idx * 4;
  const int row = i >> 11;
  const int col = i & 2047;
  const float* src;
  if (row < 2048)      src = Wq + (size_t)row * 2048 + col;
  else if (row < 2176) src = Wk + (size_t)(row - 2048) * 2048 + col;
  else                 src = Wv + (size_t)(row - 2176) * 2048 + col;
  const float4 v = *(const float4*)src;
  ushort4 o;
  o.x = f2b(v.x); o.y = f2b(v.y); o.z = f2b(v.z); o.w = f2b(v.w);
  *(ushort4*)(Wcat + i) = o;
  if (idx < NQKV)
    bcat[idx] = (idx < 2048) ? bq[idx] : (idx < 2176) ? bk[idx - 2048] : bv[idx - 2176];
}

// Vt[b][d][s] = QKV[b*S+s][2176+d] -- LDS-tiled transpose, 64 s x 128 d / block
__global__ __launch_bounds__(256)
void transpose_v(const unsigned short* __restrict__ QKV,
                 unsigned short* __restrict__ Vt) {
  __shared__ unsigned short tile[64][136];
  const int tid = threadIdx.x;
  const int s0  = blockIdx.x * 64;
  const int b   = blockIdx.y;
  const int row = tid >> 2;
  const int cb  = (tid & 3) * 32;
  const unsigned short* src = QKV + (size_t)(b * S_LEN + s0 + row) * NQKV + 2176 + cb;
#pragma unroll
  for (int i = 0; i < 4; ++i)
    *(bf16x8*)&tile[row][cb + i * 8] = *(const bf16x8*)(src + i * 8);
  __syncthreads();
  const int d  = tid >> 1;
  const int sc = (tid & 1) * 32;
  unsigned short* dst = Vt + ((size_t)b * D_ + d) * S_LEN + s0 + sc;
#pragma unroll
  for (int i = 0; i < 4; ++i) {
    bf16x8 vv;
#pragma unroll
    for (int e = 0; e < 8; ++e) vv[e] = tile[sc + i * 8 + e][d];
    *(bf16x8*)(dst + i * 8) = vv;
  }
}

// ---------------- NT GEMM (m97 structure, unchanged) ----------------

template <int OUT_F32>
__global__ __launch_bounds__(256)
void gemm_nt(const unsigned short* __restrict__ A,
             const unsigned short* __restrict__ Bm,
             const float* __restrict__ bias,
             void* __restrict__ Cv,
             int M, int N, int K) {
  __shared__ unsigned short As[128 * 32];
  __shared__ unsigned short Bs[128 * 32];
  const int tid  = threadIdx.x;
  const int lane = tid & 63;
  const int wv   = tid >> 6;
  const int wr   = wv >> 1, wc = wv & 1;
  const int g    = lane >> 4, r = lane & 15;
  const int m0   = blockIdx.y * 128;
  const int n0   = blockIdx.x * 128;

  const unsigned short* ga0 = A  + (size_t)(m0 + (tid >> 2)) * K + (tid & 3) * 8;
  const unsigned short* ga1 = ga0 + (size_t)64 * K;
  const unsigned short* gb0 = Bm + (size_t)(n0 + (tid >> 2)) * K + (tid & 3) * 8;
  const unsigned short* gb1 = gb0 + (size_t)64 * K;

  f32x4 acc[4][4] = {};

  for (int k0 = 0; k0 < K; k0 += 32) {
    __syncthreads();
    load_lds16(ga0 + k0, &As[tid * 8]);
    load_lds16(ga1 + k0, &As[2048 + tid * 8]);
    load_lds16(gb0 + k0, &Bs[tid * 8]);
    load_lds16(gb1 + k0, &Bs[2048 + tid * 8]);
    __syncthreads();
    bf16x8 af[4], bfr[4];
#pragma unroll
    for (int i = 0; i < 4; ++i)
      af[i] = *(const bf16x8*)&As[(wr * 64 + i * 16 + r) * 32 + g * 8];
#pragma unroll
    for (int i = 0; i < 4; ++i)
      bfr[i] = *(const bf16x8*)&Bs[(wc * 64 + i * 16 + r) * 32 + g * 8];
#pragma unroll
    for (int i = 0; i < 4; ++i)
#pragma unroll
      for (int j = 0; j < 4; ++j)
        acc[i][j] = mfma16(af[i], bfr[j], acc[i][j]);
  }

#pragma unroll
  for (int i = 0; i < 4; ++i) {
    const int row = m0 + wr * 64 + i * 16 + g * 4;
#pragma unroll
    for (int j = 0; j < 4; ++j) {
      const int col = n0 + wc * 64 + j * 16 + r;
      const float bb = bias[col];
#pragma unroll
      for (int e = 0; e < 4; ++e) {
        const float v = acc[i][j][e] + bb;
        if (OUT_F32) ((float*)Cv)[(size_t)(row + e) * N + col] = v;
        else ((unsigned short*)Cv)[(size_t)(row + e) * N + col] = f2b(v);
      }
    }
  }
}

// ---------------- flash attention (causal, MQA) ----------------
// 64 Q rows/block (4 waves x 16), KVBLK=64, double-buffered LDS, XOR-swizzled
// K and V tiles, defer-max online softmax, diagonal-tile wave-uniform skips.

__global__ __launch_bounds__(256)
void mqa_attn(const unsigned short* __restrict__ QKV,
              const unsigned short* __restrict__ Vt,
              unsigned short* __restrict__ Ob) {
  __shared__ __align__(16) char Ks[2][64 * 256];    // [kv][d] 256B rows, swizzled
  __shared__ __align__(16) char Vs[2][128 * 128];   // [d][kv] 128B rows, swizzled
  __shared__ unsigned short Pl[4][16 * 72];         // per-wave P [q][kv], stride 72

  const int tid  = threadIdx.x;
  const int lane = tid & 63;
  const int wv   = tid >> 6;
  const int g    = lane >> 4;
  const int c    = lane & 15;
  const int qt   = 31 - blockIdx.x;      // heavy blocks dispatch first
  const int bh   = blockIdx.y;
  const int b    = bh >> 4;
  const int h    = bh & 15;
  const int qrow0 = qt * 64 + wv * 16;

  unsigned short* pw = &Pl[wv][0];

  // Q fragments (A-layout: row=c, k=kk*32+g*8), held for the whole loop
  bf16x8 qf[4];
  {
    const unsigned short* qp =
        QKV + (size_t)(b * S_LEN + qrow0 + c) * NQKV + h * D_ + g * 8;
#pragma unroll
    for (int kk = 0; kk < 4; ++kk) qf[kk] = *(const bf16x8*)(qp + kk * 32);
  }

  const unsigned short* kbase = QKV + (size_t)(b * S_LEN) * NQKV + 2048;
  const unsigned short* vtb   = Vt + (size_t)b * D_ * S_LEN;

  f32x4 acc[8];
#pragma unroll
  for (int i = 0; i < 8; ++i) { acc[i][0]=0.f; acc[i][1]=0.f; acc[i][2]=0.f; acc[i][3]=0.f; }
  float mrow[4] = {-__builtin_inff(), -__builtin_inff(), -__builtin_inff(), -__builtin_inff()};
  float lrow[4] = {0.f, 0.f, 0.f, 0.f};

  const float sscale = 0.08838834764831845f * 1.4426950408889634f;  // scale*log2e
  const int nt = qt + 1;                 // KV tiles of 64
  const int xr = (c & 7) << 4;

  // ---- staging: 1024 16B chunks each for K (64x256B) and V (128x128B) ----
#define STAGE(bufi, t)                                                         \
  {                                                                            \
    const int kv0_ = (t) * 64;                                                 \
    _Pragma("unroll")                                                          \
    for (int i_ = 0; i_ < 4; ++i_) {                                           \
      const int ch_ = tid + 256 * i_;                                          \
      const int kr_ = ch_ >> 4;                                                \
      const int kc_ = ((ch_ & 15) << 4) ^ ((kr_ & 7) << 4);                    \
      load_lds16((const char*)(kbase + (size_t)(kv0_ + kr_) * NQKV) + kc_,     \
                 Ks[bufi] + ch_ * 16);                                         \
      const int vr_ = ch_ >> 3;                                                \
      const int vc_ = ((ch_ & 7) << 4) ^ ((vr_ & 7) << 4);                     \
      load_lds16((const char*)(vtb + (size_t)vr_ * S_LEN + kv0_) + vc_,        \
                 Vs[bufi] + ch_ * 16);                                         \
    }                                                                          \
  }

  STAGE(0, 0);
  int cur = 0;

  for (int t = 0; t < nt; ++t) {
    __syncthreads();                       // publishes buf[cur] (vmcnt drained)
    if (t + 1 < nt) STAGE(cur ^ 1, t + 1); // prefetch overlaps compute below

    const char* ksb = Ks[cur];
    const char* vsb = Vs[cur];
    const int kv0 = t * 64;
    const bool lastT = (t == nt - 1);
    const int mmax = lastT ? wv : 3;       // diagonal tile: skip chunks m > wv

    // QK^T: s[m] covers kv columns kv0+16m+c
    f32x4 s0={0.f,0.f,0.f,0.f}, s1={0.f,0.f,0.f,0.f},
          s2={0.f,0.f,0.f,0.f}, s3={0.f,0.f,0.f,0.f};
#pragma unroll
    for (int kk = 0; kk < 4; ++kk) {
      const int cb = (kk * 64 + g * 16) ^ xr;
      s0 = mfma16(qf[kk], *(const bf16x8*)(ksb + c * 256 + cb), s0);
      if (1 <= mmax) s1 = mfma16(qf[kk], *(const bf16x8*)(ksb + (c + 16) * 256 + cb), s1);
      if (2 <= mmax) s2 = mfma16(qf[kk], *(const bf16x8*)(ksb + (c + 32) * 256 + cb), s2);
      if (3 <= mmax) s3 = mfma16(qf[kk], *(const bf16x8*)(ksb + (c + 48) * 256 + cb), s3);
    }

    // online softmax (exp2 domain), defer-max THR=8
#pragma unroll
    for (int j = 0; j < 4; ++j) {
      const int qg = qrow0 + 4 * g + j;
      float a0 = s0[j] * sscale, a1 = s1[j] * sscale,
            a2 = s2[j] * sscale, a3 = s3[j] * sscale;
      if (lastT) {
        a0 = (kv0 + c      <= qg) ? a0 : -__builtin_inff();
        a1 = (1 <= mmax && kv0 + 16 + c <= qg) ? a1 : -__builtin_inff();
        a2 = (2 <= mmax && kv0 + 32 + c <= qg) ? a2 : -__builtin_inff();
        a3 = (3 <= mmax && kv0 + 48 + c <= qg) ? a3 : -__builtin_inff();
      }
      float pm = fmaxf(fmaxf(a0, a1), fmaxf(a2, a3));
      pm = fmaxf(pm, __shfl_xor(pm, 1));
      pm = fmaxf(pm, __shfl_xor(pm, 2));
      pm = fmaxf(pm, __shfl_xor(pm, 4));
      pm = fmaxf(pm, __shfl_xor(pm, 8));
      const bool need = pm > mrow[j] + 8.f;
      const float mnew = need ? pm : mrow[j];
      if (__any(need)) {
        const float scal = need ? __builtin_amdgcn_exp2f(mrow[j] - pm) : 1.f;
#pragma unroll
        for (int nf = 0; nf < 8; ++nf) acc[nf][j] *= scal;
        lrow[j] *= scal;
        mrow[j] = mnew;
      }
      const float p0 = __builtin_amdgcn_exp2f(a0 - mnew);
      const float p1 = __builtin_amdgcn_exp2f(a1 - mnew);
      const float p2 = __builtin_amdgcn_exp2f(a2 - mnew);
      const float p3 = __builtin_amdgcn_exp2f(a3 - mnew);
      float rs = (p0 + p1) + (p2 + p3);
      rs += __shfl_xor(rs, 1);
      rs += __shfl_xor(rs, 2);
      rs += __shfl_xor(rs, 4);
      rs += __shfl_xor(rs, 8);
      lrow[j] += rs;
      const int pr = (4 * g + j) * 72;
      pw[pr + c]      = f2b(p0);
      pw[pr + 16 + c] = f2b(p1);
      pw[pr + 32 + c] = f2b(p2);
      pw[pr + 48 + c] = f2b(p3);
    }
    asm volatile("s_waitcnt lgkmcnt(0)" ::: "memory");
    __builtin_amdgcn_sched_barrier(0);
    const bf16x8 pf0 = *(const bf16x8*)&pw[c * 72 + g * 8];
    const bf16x8 pf1 = *(const bf16x8*)&pw[c * 72 + 32 + g * 8];

    // PV: acc[nf] += P(16x64) * Vt(64x16 per nf)
#pragma unroll
    for (int nf = 0; nf < 8; ++nf) {
      const bf16x8 v0 = *(const bf16x8*)(vsb + (nf * 16 + c) * 128 + ((g * 16) ^ xr));
      acc[nf] = mfma16(pf0, v0, acc[nf]);
    }
    if (!(lastT && wv < 2)) {              // waves 0,1: upper half fully masked
#pragma unroll
      for (int nf = 0; nf < 8; ++nf) {
        const bf16x8 v1 = *(const bf16x8*)(vsb + (nf * 16 + c) * 128 + ((64 + g * 16) ^ xr));
        acc[nf] = mfma16(pf1, v1, acc[nf]);
      }
    }
    cur ^= 1;
  }

  // epilogue: normalize, store bf16 [4096][2048]
  unsigned short* op = Ob + (size_t)(b * S_LEN + qrow0 + 4 * g) * HID_ + h * D_ + c;
#pragma unroll
  for (int j = 0; j < 4; ++j) {
    const float inv = 1.0f / lrow[j];
#pragma unroll
    for (int nf = 0; nf < 8; ++nf)
      op[(size_t)j * HID_ + nf * 16] = f2b(acc[nf][j] * inv);
  }
#undef STAGE
}

// ---------------- launcher ----------------

extern "C" void kernel_launch(void* const* d_in, const int* in_sizes, int n_in,
                              void* d_out, int out_size, void* d_ws, size_t ws_size,
                              hipStream_t stream) {
  (void)in_sizes; (void)n_in; (void)out_size; (void)ws_size;
  const float* x  = (const float*)d_in[0];
  const float* Wq = (const float*)d_in[2];
  const float* bq = (const float*)d_in[3];
  const float* Wk = (const float*)d_in[4];
  const float* bk = (const float*)d_in[5];
  const float* Wv = (const float*)d_in[6];
  const float* bv = (const float*)d_in[7];
  const float* Wo = (const float*)d_in[8];
  const float* bo = (const float*)d_in[9];
  float* out = (float*)d_out;

  char* p = (char*)d_ws;
  unsigned short* xb   = (unsigned short*)p;  p += (size_t)4096 * 2048 * 2;
  unsigned short* Wcat = (unsigned short*)p;  p += (size_t)2304 * 2048 * 2;
  float*          bcat = (float*)p;           p += 16384;
  unsigned short* Wob  = (unsigned short*)p;  p += (size_t)2048 * 2048 * 2;
  unsigned short* QKV  = (unsigned short*)p;  p += (size_t)4096 * 2304 * 2;
  unsigned short* Vt   = (unsigned short*)p;  p += (size_t)2 * 128 * 2048 * 2;
  unsigned short* Ob   = xb;  // xb dead after gemm1

  cast_f32_bf16_k<<<8192, 256, 0, stream>>>(x, xb, 2097152);
  build_wcat_k<<<4608, 256, 0, stream>>>(Wq, Wk, Wv, bq, bk, bv, Wcat, bcat);
  cast_f32_bf16_k<<<4096, 256, 0, stream>>>(Wo, Wob, 1048576);
  gemm_nt<0><<<dim3(18, 32), 256, 0, stream>>>(xb, Wcat, bcat, QKV, 4096, NQKV, 2048);
  transpose_v<<<dim3(32, 2), 256, 0, stream>>>(QKV, Vt);
  mqa_attn<<<dim3(32, 32), 256, 0, stream>>>(QKV, Vt, Ob);
  gemm_nt<1><<<dim3(16, 32), 256, 0, stream>>>(Ob, Wob, bo, out, 4096, 2048, 2048);
}

// Round 3
// 253.106 us; speedup vs baseline: 1.4310x; 1.2545x over previous
//
#include <hip/hip_runtime.h>

// MQA: B=2, S=2048, HID=2048, H=16, D=128 (single KV head), causal.
// Pipeline: cast -> fused QKV NT-GEMM (bf16 MFMA) -> V transpose -> kmax ->
//           flash attention (swapped QK, Cauchy-bound softmax, no reductions)
//           -> out NT-GEMM.

#define S_LEN 2048
#define HID_  2048
#define D_    128
#define NQKV  2304   // 2048 Q + 128 K + 128 V columns

typedef __attribute__((ext_vector_type(8))) short bf16x8;
typedef __attribute__((ext_vector_type(4))) short s16x4;
typedef __attribute__((ext_vector_type(4))) float f32x4;

__device__ __forceinline__ unsigned short f2b(float f) {
  union { float f; unsigned int u; } a; a.f = f;
  unsigned int u = a.u;
  return (unsigned short)((u + 0x7fffu + ((u >> 16) & 1u)) >> 16);  // RNE
}

__device__ __forceinline__ float b2f(unsigned short s) {
  union { unsigned int u; float f; } a; a.u = ((unsigned int)s) << 16;
  return a.f;
}

__device__ __forceinline__ void load_lds16(const void* g, void* l) {
  __builtin_amdgcn_global_load_lds(
      (const __attribute__((address_space(1))) void*)g,
      (__attribute__((address_space(3))) void*)l, 16, 0, 0);
}

__device__ __forceinline__ f32x4 mfma16(bf16x8 a, bf16x8 b, f32x4 c) {
  return __builtin_amdgcn_mfma_f32_16x16x32_bf16(a, b, c, 0, 0, 0);
}

// ---------------- casts / packing ----------------

__global__ void cast_f32_bf16_k(const float* __restrict__ in,
                                unsigned short* __restrict__ out, int n4) {
  const int idx = blockIdx.x * 256 + threadIdx.x;
  if (idx < n4) {
    const float4 v = ((const float4*)in)[idx];
    ushort4 o;
    o.x = f2b(v.x); o.y = f2b(v.y); o.z = f2b(v.z); o.w = f2b(v.w);
    ((ushort4*)out)[idx] = o;
  }
}

__global__ void build_wcat_k(const float* __restrict__ Wq,
                             const float* __restrict__ Wk,
                             const float* __restrict__ Wv,
                             const float* __restrict__ bq,
                             const float* __restrict__ bk,
                             const float* __restrict__ bv,
                             unsigned short* __restrict__ Wcat,
                             float* __restrict__ bcat,
                             float* __restrict__ Kmax) {
  const int idx = blockIdx.x * 256 + threadIdx.x;
  const int i = idx * 4;
  const int row = i >> 11;
  const int col = i & 2047;
  const float* src;
  if (row < 2048)      src = Wq + (size_t)row * 2048 + col;
  else if (row < 2176) src = Wk + (size_t)(row - 2048) * 2048 + col;
  else                 src = Wv + (size_t)(row - 2176) * 2048 + col;
  const float4 v = *(const float4*)src;
  ushort4 o;
  o.x = f2b(v.x); o.y = f2b(v.y); o.z = f2b(v.z); o.w = f2b(v.w);
  *(ushort4*)(Wcat + i) = o;
  if (idx < NQKV)
    bcat[idx] = (idx < 2048) ? bq[idx] : (idx < 2176) ? bk[idx - 2048] : bv[idx - 2176];
  if (idx < 2) Kmax[idx] = 0.f;   // re-init every launch (runs before kmax_k)
}

// Vt[b][d][s] = QKV[b*S+s][2176+d] -- LDS-tiled transpose
__global__ __launch_bounds__(256)
void transpose_v(const unsigned short* __restrict__ QKV,
                 unsigned short* __restrict__ Vt) {
  __shared__ unsigned short tile[64][136];
  const int tid = threadIdx.x;
  const int s0  = blockIdx.x * 64;
  const int b   = blockIdx.y;
  const int row = tid >> 2;
  const int cb  = (tid & 3) * 32;
  const unsigned short* src = QKV + (size_t)(b * S_LEN + s0 + row) * NQKV + 2176 + cb;
#pragma unroll
  for (int i = 0; i < 4; ++i)
    *(bf16x8*)&tile[row][cb + i * 8] = *(const bf16x8*)(src + i * 8);
  __syncthreads();
  const int d  = tid >> 1;
  const int sc = (tid & 1) * 32;
  unsigned short* dst = Vt + ((size_t)b * D_ + d) * S_LEN + s0 + sc;
#pragma unroll
  for (int i = 0; i < 4; ++i) {
    bf16x8 vv;
#pragma unroll
    for (int e = 0; e < 8; ++e) vv[e] = tile[sc + i * 8 + e][d];
    *(bf16x8*)(dst + i * 8) = vv;
  }
}

// max_s ||k[b,s]||^2 -> Kmax[b] (as float bits via atomicMax on uint)
__global__ __launch_bounds__(256)
void kmax_k(const unsigned short* __restrict__ QKV, float* __restrict__ Kmax) {
  __shared__ float red[256];
  const int tid = threadIdx.x;
  const int b = blockIdx.x >> 3;
  const int s = (blockIdx.x & 7) * 256 + tid;
  const unsigned short* kp = QKV + (size_t)(b * S_LEN + s) * NQKV + 2048;
  float sum = 0.f;
#pragma unroll
  for (int i = 0; i < 16; ++i) {
    bf16x8 v = *(const bf16x8*)(kp + i * 8);
#pragma unroll
    for (int e = 0; e < 8; ++e) { const float f = b2f((unsigned short)v[e]); sum += f * f; }
  }
  red[tid] = sum;
  __syncthreads();
  for (int off = 128; off > 0; off >>= 1) {
    if (tid < off) red[tid] = fmaxf(red[tid], red[tid + off]);
    __syncthreads();
  }
  if (tid == 0) atomicMax((unsigned int*)(Kmax + b), __float_as_uint(red[0]));
}

// ---------------- NT GEMM (m97 structure, unchanged) ----------------

template <int OUT_F32>
__global__ __launch_bounds__(256)
void gemm_nt(const unsigned short* __restrict__ A,
             const unsigned short* __restrict__ Bm,
             const float* __restrict__ bias,
             void* __restrict__ Cv,
             int M, int N, int K) {
  __shared__ unsigned short As[128 * 32];
  __shared__ unsigned short Bs[128 * 32];
  const int tid  = threadIdx.x;
  const int lane = tid & 63;
  const int wv   = tid >> 6;
  const int wr   = wv >> 1, wc = wv & 1;
  const int g    = lane >> 4, r = lane & 15;
  const int m0   = blockIdx.y * 128;
  const int n0   = blockIdx.x * 128;

  const unsigned short* ga0 = A  + (size_t)(m0 + (tid >> 2)) * K + (tid & 3) * 8;
  const unsigned short* ga1 = ga0 + (size_t)64 * K;
  const unsigned short* gb0 = Bm + (size_t)(n0 + (tid >> 2)) * K + (tid & 3) * 8;
  const unsigned short* gb1 = gb0 + (size_t)64 * K;

  f32x4 acc[4][4] = {};

  for (int k0 = 0; k0 < K; k0 += 32) {
    __syncthreads();
    load_lds16(ga0 + k0, &As[tid * 8]);
    load_lds16(ga1 + k0, &As[2048 + tid * 8]);
    load_lds16(gb0 + k0, &Bs[tid * 8]);
    load_lds16(gb1 + k0, &Bs[2048 + tid * 8]);
    __syncthreads();
    bf16x8 af[4], bfr[4];
#pragma unroll
    for (int i = 0; i < 4; ++i)
      af[i] = *(const bf16x8*)&As[(wr * 64 + i * 16 + r) * 32 + g * 8];
#pragma unroll
    for (int i = 0; i < 4; ++i)
      bfr[i] = *(const bf16x8*)&Bs[(wc * 64 + i * 16 + r) * 32 + g * 8];
#pragma unroll
    for (int i = 0; i < 4; ++i)
#pragma unroll
      for (int j = 0; j < 4; ++j)
        acc[i][j] = mfma16(af[i], bfr[j], acc[i][j]);
  }

#pragma unroll
  for (int i = 0; i < 4; ++i) {
    const int row = m0 + wr * 64 + i * 16 + g * 4;
#pragma unroll
    for (int j = 0; j < 4; ++j) {
      const int col = n0 + wc * 64 + j * 16 + r;
      const float bb = bias[col];
#pragma unroll
      for (int e = 0; e < 4; ++e) {
        const float v = acc[i][j][e] + bb;
        if (OUT_F32) ((float*)Cv)[(size_t)(row + e) * N + col] = v;
        else ((unsigned short*)Cv)[(size_t)(row + e) * N + col] = f2b(v);
      }
    }
  }
}

// ---------------- flash attention (causal, MQA) ----------------
// Swapped QK^T (lane owns q=c, kv=16m+4g+r), Cauchy-bound softmax (no max
// tracking, no cross-lane reductions), row-sum via ones-MFMA, packed b64
// P writes, KVBLK=64 double-buffered swizzled LDS.

__global__ __launch_bounds__(256)
void mqa_attn(const unsigned short* __restrict__ QKV,
              const unsigned short* __restrict__ Vt,
              const float* __restrict__ Kmax,
              unsigned short* __restrict__ Ob) {
  __shared__ __align__(16) char Ks[2][64 * 256];    // [kv][d] 256B rows, swizzled
  __shared__ __align__(16) char Vs[2][128 * 128];   // [d][kv] 128B rows, swizzled
  __shared__ unsigned short Pl[4][16 * 72];         // per-wave P [q][kv], stride 72

  const int tid  = threadIdx.x;
  const int lane = tid & 63;
  const int wv   = tid >> 6;
  const int g    = lane >> 4;
  const int c    = lane & 15;
  const int qt   = 31 - blockIdx.x;      // heavy blocks dispatch first
  const int bh   = blockIdx.y;
  const int b    = bh >> 4;
  const int h    = bh & 15;
  const int qrow0 = qt * 64 + wv * 16;

  unsigned short* pw = &Pl[wv][0];

  // Q fragments: lane holds Q[q=qrow0+c][d = kk*32 + g*8 + e]
  bf16x8 qf[4];
  {
    const unsigned short* qp =
        QKV + (size_t)(b * S_LEN + qrow0 + c) * NQKV + h * D_ + g * 8;
#pragma unroll
    for (int kk = 0; kk < 4; ++kk) qf[kk] = *(const bf16x8*)(qp + kk * 32);
  }

  // Cauchy-Schwarz bound (exp2 domain): m0 = sscale*||q||*max||k|| + 1
  const float sscale = 0.08838834764831845f * 1.4426950408889634f;  // scale*log2e
  float qn2 = 0.f;
#pragma unroll
  for (int kk = 0; kk < 4; ++kk)
#pragma unroll
    for (int e = 0; e < 8; ++e) {
      const float qv = b2f((unsigned short)qf[kk][e]);
      qn2 += qv * qv;
    }
  qn2 += __shfl_xor(qn2, 16);
  qn2 += __shfl_xor(qn2, 32);
  const float m0c = sqrtf(qn2) * sqrtf(Kmax[b]) * sscale + 1.0f;

  const unsigned short* kbase = QKV + (size_t)(b * S_LEN) * NQKV + 2048;
  const unsigned short* vtb   = Vt + (size_t)b * D_ * S_LEN;

  f32x4 acc[8];
#pragma unroll
  for (int i = 0; i < 8; ++i) { acc[i][0]=0.f; acc[i][1]=0.f; acc[i][2]=0.f; acc[i][3]=0.f; }
  f32x4 accl = {0.f, 0.f, 0.f, 0.f};     // row sums (denominator)

  bf16x8 onesf;
#pragma unroll
  for (int e = 0; e < 8; ++e) onesf[e] = (short)0x3F80;  // bf16 1.0

  const int nt = qt + 1;                 // KV tiles of 64
  const int xr = (c & 7) << 4;
  const int qloc = qrow0 + c;            // this lane's absolute q row

#define STAGE(bufi, t)                                                         \
  {                                                                            \
    const int kv0_ = (t) * 64;                                                 \
    _Pragma("unroll")                                                          \
    for (int i_ = 0; i_ < 4; ++i_) {                                           \
      const int ch_ = tid + 256 * i_;                                          \
      const int kr_ = ch_ >> 4;                                                \
      const int kc_ = ((ch_ & 15) << 4) ^ ((kr_ & 7) << 4);                    \
      load_lds16((const char*)(kbase + (size_t)(kv0_ + kr_) * NQKV) + kc_,     \
                 Ks[bufi] + ch_ * 16);                                         \
      const int vr_ = ch_ >> 3;                                                \
      const int vc_ = ((ch_ & 7) << 4) ^ ((vr_ & 7) << 4);                     \
      load_lds16((const char*)(vtb + (size_t)vr_ * S_LEN + kv0_) + vc_,        \
                 Vs[bufi] + ch_ * 16);                                         \
    }                                                                          \
  }

  STAGE(0, 0);
  int cur = 0;

  for (int t = 0; t < nt; ++t) {
    __syncthreads();                       // publishes buf[cur]
    if (t + 1 < nt) STAGE(cur ^ 1, t + 1); // prefetch overlaps compute

    const char* ksb = Ks[cur];
    const char* vsb = Vs[cur];
    const int kv0 = t * 64;
    const bool lastT = (t == nt - 1);
    const int mmax = lastT ? wv : 3;       // diagonal tile: skip chunks m > wv

    // Swapped QK^T: s_m = K_m * Q ; D[row=kv=16m+4g+r][col=q=c]
    f32x4 s0={0.f,0.f,0.f,0.f}, s1={0.f,0.f,0.f,0.f},
          s2={0.f,0.f,0.f,0.f}, s3={0.f,0.f,0.f,0.f};
#pragma unroll
    for (int kk = 0; kk < 4; ++kk) {
      const int cb = (kk * 64 + g * 16) ^ xr;
      s0 = mfma16(*(const bf16x8*)(ksb + c * 256 + cb), qf[kk], s0);
      if (1 <= mmax) s1 = mfma16(*(const bf16x8*)(ksb + (c + 16) * 256 + cb), qf[kk], s1);
      if (2 <= mmax) s2 = mfma16(*(const bf16x8*)(ksb + (c + 32) * 256 + cb), qf[kk], s2);
      if (3 <= mmax) s3 = mfma16(*(const bf16x8*)(ksb + (c + 48) * 256 + cb), qf[kk], s3);
    }

    // p = exp2(s*sscale - m0) ; packed b64 write P[q=c][kv=16m+4g+r]
#define DOP(mi, sv)                                                            \
    {                                                                          \
      s16x4 pk;                                                                \
      _Pragma("unroll")                                                        \
      for (int r = 0; r < 4; ++r) {                                            \
        float a = sv[r] * sscale - m0c;                                        \
        if (lastT) {                                                           \
          const int kva = kv0 + 16 * mi + 4 * g + r;                           \
          if (kva > qloc) a = -__builtin_inff();                               \
        }                                                                      \
        pk[r] = (short)f2b(__builtin_amdgcn_exp2f(a));                         \
      }                                                                        \
      *(s16x4*)((char*)pw + c * 144 + mi * 32 + g * 8) = pk;                   \
    }
    DOP(0, s0) DOP(1, s1) DOP(2, s2) DOP(3, s3)
#undef DOP

    asm volatile("s_waitcnt lgkmcnt(0)" ::: "memory");
    __builtin_amdgcn_sched_barrier(0);
    const bf16x8 pf0 = *(const bf16x8*)&pw[c * 72 + g * 8];
    const bf16x8 pf1 = *(const bf16x8*)&pw[c * 72 + 32 + g * 8];

    // denominator: accl[r] = sum_kv P[q=4g+r][kv]  (ones-MFMA)
    accl = mfma16(pf0, onesf, accl);
    accl = mfma16(pf1, onesf, accl);

    // PV: acc[nf] += P(16x64) * V(64x16 per nf); D[row=q=4g+r][col=d=c]
#pragma unroll
    for (int nf = 0; nf < 8; ++nf) {
      const bf16x8 v0 = *(const bf16x8*)(vsb + (nf * 16 + c) * 128 + ((g * 16) ^ xr));
      acc[nf] = mfma16(pf0, v0, acc[nf]);
    }
    if (!(lastT && wv < 2)) {              // waves 0,1: upper half fully masked
#pragma unroll
      for (int nf = 0; nf < 8; ++nf) {
        const bf16x8 v1 = *(const bf16x8*)(vsb + (nf * 16 + c) * 128 + ((64 + g * 16) ^ xr));
        acc[nf] = mfma16(pf1, v1, acc[nf]);
      }
    }
    cur ^= 1;
  }

  // epilogue: normalize, store bf16 [4096][2048]
  unsigned short* op = Ob + (size_t)(b * S_LEN + qrow0 + 4 * g) * HID_ + h * D_ + c;
#pragma unroll
  for (int j = 0; j < 4; ++j) {
    const float inv = 1.0f / accl[j];
#pragma unroll
    for (int nf = 0; nf < 8; ++nf)
      op[(size_t)j * HID_ + nf * 16] = f2b(acc[nf][j] * inv);
  }
#undef STAGE
}

// ---------------- launcher ----------------

extern "C" void kernel_launch(void* const* d_in, const int* in_sizes, int n_in,
                              void* d_out, int out_size, void* d_ws, size_t ws_size,
                              hipStream_t stream) {
  (void)in_sizes; (void)n_in; (void)out_size; (void)ws_size;
  const float* x  = (const float*)d_in[0];
  const float* Wq = (const float*)d_in[2];
  const float* bq = (const float*)d_in[3];
  const float* Wk = (const float*)d_in[4];
  const float* bk = (const float*)d_in[5];
  const float* Wv = (const float*)d_in[6];
  const float* bv = (const float*)d_in[7];
  const float* Wo = (const float*)d_in[8];
  const float* bo = (const float*)d_in[9];
  float* out = (float*)d_out;

  char* p = (char*)d_ws;
  unsigned short* xb   = (unsigned short*)p;  p += (size_t)4096 * 2048 * 2;
  unsigned short* Wcat = (unsigned short*)p;  p += (size_t)2304 * 2048 * 2;
  float*          bcat = (float*)p;           p += 16384;
  unsigned short* Wob  = (unsigned short*)p;  p += (size_t)2048 * 2048 * 2;
  unsigned short* QKV  = (unsigned short*)p;  p += (size_t)4096 * 2304 * 2;
  unsigned short* Vt   = (unsigned short*)p;  p += (size_t)2 * 128 * 2048 * 2;
  float*          Kmax = (float*)p;           p += 64;
  unsigned short* Ob   = xb;  // xb dead after gemm1

  cast_f32_bf16_k<<<8192, 256, 0, stream>>>(x, xb, 2097152);
  build_wcat_k<<<4608, 256, 0, stream>>>(Wq, Wk, Wv, bq, bk, bv, Wcat, bcat, Kmax);
  cast_f32_bf16_k<<<4096, 256, 0, stream>>>(Wo, Wob, 1048576);
  gemm_nt<0><<<dim3(18, 32), 256, 0, stream>>>(xb, Wcat, bcat, QKV, 4096, NQKV, 2048);
  transpose_v<<<dim3(32, 2), 256, 0, stream>>>(QKV, Vt);
  kmax_k<<<16, 256, 0, stream>>>(QKV, Kmax);
  mqa_attn<<<dim3(32, 32), 256, 0, stream>>>(QKV, Vt, Kmax, Ob);
  gemm_nt<1><<<dim3(16, 32), 256, 0, stream>>>(Ob, Wob, bo, out, 4096, 2048, 2048);
}